// Round 3
// baseline (91.764 us; speedup 1.0000x reference)
//
#include <hip/hip_runtime.h>
#include <math.h>

#define BATCH    32
#define NHEADS   32
#define KVHEADS  8
#define GRP      4      // NHEADS / KVHEADS
#define HSZ      128
#define BLKSZ    16
#define BPS      128    // blocks per seq
#define NTHREADS 512
#define NPROC    16     // half-wave processors per WG
#define CHUNK    256    // tokens per split
#define NSPLIT   8      // 2048 / CHUNK
#define ITERS    (CHUNK / NPROC)   // 16
#define SCALE    0.08838834764831843f   // 1/sqrt(128)

__device__ __forceinline__ float hsum32(float v) {
    v += __shfl_xor(v, 1);
    v += __shfl_xor(v, 2);
    v += __shfl_xor(v, 4);
    v += __shfl_xor(v, 8);
    v += __shfl_xor(v, 16);   // stays within the 32-lane half
    return v;
}

// ---------------- split kernel: one WG per (b, kvh, chunk) ----------------
__global__ __launch_bounds__(NTHREADS) void pa_partial(
    const float* __restrict__ query,
    const float* __restrict__ k_new,
    const float* __restrict__ v_new,
    const float* __restrict__ k_cache,
    const float* __restrict__ v_cache,
    const int*  __restrict__ block_tables,
    const int*  __restrict__ ctx_lens,
    float* __restrict__ pm, float* __restrict__ pl, float* __restrict__ po)
{
    const int wg    = blockIdx.x;
    const int chunk = wg & (NSPLIT - 1);
    const int kvh   = (wg >> 3) & (KVHEADS - 1);
    const int b     = wg >> 6;
    const int ctx   = ctx_lens[b];
    const int t0    = chunk * CHUNK;
    if (t0 > ctx) return;                 // inactive split: reduce never reads it

    const int tid  = threadIdx.x;
    const int sub  = tid & 31;
    const int proc = tid >> 5;

    __shared__ float q_s[GRP][HSZ];
    __shared__ float kn_s[HSZ];
    __shared__ int   bt_s[CHUNK / BLKSZ];
    __shared__ float sp[CHUNK][GRP];      // scores, then probs in place (4 KB)
    __shared__ float redm[8], redl[8];
    __shared__ float o_s[NPROC][GRP][HSZ];

    // ---- init scores to -inf (invalid rows contribute p=0) ----
    {
        float* s1 = &sp[0][0];
        s1[tid]       = -INFINITY;
        s1[tid + 512] = -INFINITY;
    }
    // ---- RoPE (pos = ctx+1) for q heads and new k; stage block table ----
    {
        const float p = (float)(ctx + 1);
        if (tid < 320) {
            const int   i    = tid & 63;
            const float invf = exp2f(-((float)i / 64.0f) * 13.287712379549449f); // 10000^(-2i/128)
            float s_, c_;
            sincosf(p * invf, &s_, &c_);
            if (tid < 256) {
                const int g = tid >> 6;
                const float* qp = query + ((size_t)b * NHEADS + kvh * GRP + g) * HSZ;
                const float x1 = qp[i], x2 = qp[i + 64];
                q_s[g][i]      = x1 * c_ - x2 * s_;
                q_s[g][i + 64] = x2 * c_ + x1 * s_;
            } else {
                const float* kp = k_new + ((size_t)b * KVHEADS + kvh) * HSZ;
                const float x1 = kp[i], x2 = kp[i + 64];
                kn_s[i]      = x1 * c_ - x2 * s_;
                kn_s[i + 64] = x2 * c_ + x1 * s_;
            }
        } else if (tid < 320 + CHUNK / BLKSZ) {
            bt_s[tid - 320] = block_tables[b * BPS + (t0 >> 4) + (tid - 320)];
        }
    }
    __syncthreads();

    const int d0 = sub << 2;
    float4 qf[GRP];
#pragma unroll
    for (int g = 0; g < GRP; ++g) {
        float4 t = *(const float4*)&q_s[g][d0];
        qf[g] = make_float4(t.x * SCALE, t.y * SCALE, t.z * SCALE, t.w * SCALE);
    }

    const int ncache = min(t0 + CHUNK, ctx) - t0;   // rows sourced from cache

    // ---- phase 1: scores (no loop-carried dependency) ----
#pragma unroll 4
    for (int i = 0; i < ITERS; ++i) {
        const int    tl  = proc + i * NPROC;
        const int    blk = bt_s[tl >> 4];
        const size_t a   = (((size_t)blk * BLKSZ + (tl & 15)) * KVHEADS + kvh) * HSZ + d0;
        const float4 kv  = *(const float4*)(k_cache + a);
        float s[GRP];
#pragma unroll
        for (int g = 0; g < GRP; ++g)
            s[g] = qf[g].x * kv.x + qf[g].y * kv.y + qf[g].z * kv.z + qf[g].w * kv.w;
#pragma unroll
        for (int g = 0; g < GRP; ++g) s[g] = hsum32(s[g]);
        if (tl < ncache && sub == 0)
            *(float4*)&sp[tl][0] = make_float4(s[0], s[1], s[2], s[3]);
    }
    // newest token (t == ctx): score from roped k_new in LDS
    if (chunk == (ctx >> 8)) {
        const int tc = ctx - t0;
        if (proc == (tc & (NPROC - 1))) {
            const float4 kv = *(const float4*)&kn_s[d0];
            float s[GRP];
#pragma unroll
            for (int g = 0; g < GRP; ++g)
                s[g] = qf[g].x * kv.x + qf[g].y * kv.y + qf[g].z * kv.z + qf[g].w * kv.w;
#pragma unroll
            for (int g = 0; g < GRP; ++g) s[g] = hsum32(s[g]);
            if (sub == 0) *(float4*)&sp[tc][0] = make_float4(s[0], s[1], s[2], s[3]);
        }
    }
    __syncthreads();

    // ---- phase 2: chunk-wide softmax (once per 256 tokens) ----
    const int g2 = tid >> 7;            // 0..3 (wave-uniform: waves 2g2, 2g2+1)
    const int t2 = (tid & 127) << 1;
    const float s0 = sp[t2][g2], s1 = sp[t2 + 1][g2];
    float mx = fmaxf(s0, s1);
    mx = fmaxf(mx, __shfl_xor(mx, 1));
    mx = fmaxf(mx, __shfl_xor(mx, 2));
    mx = fmaxf(mx, __shfl_xor(mx, 4));
    mx = fmaxf(mx, __shfl_xor(mx, 8));
    mx = fmaxf(mx, __shfl_xor(mx, 16));
    mx = fmaxf(mx, __shfl_xor(mx, 32));
    if ((tid & 63) == 0) redm[tid >> 6] = mx;
    __syncthreads();
    const float m_g = fmaxf(redm[g2 << 1], redm[(g2 << 1) + 1]);
    const float p0 = __expf(s0 - m_g);   // exp(-inf)=0 for invalid rows
    const float p1 = __expf(s1 - m_g);
    sp[t2][g2]     = p0;
    sp[t2 + 1][g2] = p1;
    float ls = p0 + p1;
    ls += __shfl_xor(ls, 1);
    ls += __shfl_xor(ls, 2);
    ls += __shfl_xor(ls, 4);
    ls += __shfl_xor(ls, 8);
    ls += __shfl_xor(ls, 16);
    ls += __shfl_xor(ls, 32);
    if ((tid & 63) == 0) redl[tid >> 6] = ls;
    __syncthreads();
    const float l_g = redl[g2 << 1] + redl[(g2 << 1) + 1];

    // ---- phase 3: PV (carried only through 4-cycle fmac) ----
    float4 o[GRP];
#pragma unroll
    for (int g = 0; g < GRP; ++g) o[g] = make_float4(0.f, 0.f, 0.f, 0.f);
#pragma unroll 4
    for (int i = 0; i < ITERS; ++i) {
        const int    tl  = proc + i * NPROC;
        const int    blk = bt_s[tl >> 4];
        const size_t a   = (((size_t)blk * BLKSZ + (tl & 15)) * KVHEADS + kvh) * HSZ + d0;
        const float4 vv  = *(const float4*)(v_cache + a);
        const float4 pv  = *(const float4*)&sp[tl][0];   // uniform per proc
        o[0].x += pv.x * vv.x; o[0].y += pv.x * vv.y; o[0].z += pv.x * vv.z; o[0].w += pv.x * vv.w;
        o[1].x += pv.y * vv.x; o[1].y += pv.y * vv.y; o[1].z += pv.y * vv.z; o[1].w += pv.y * vv.w;
        o[2].x += pv.z * vv.x; o[2].y += pv.z * vv.y; o[2].z += pv.z * vv.z; o[2].w += pv.z * vv.w;
        o[3].x += pv.w * vv.x; o[3].y += pv.w * vv.y; o[3].z += pv.w * vv.z; o[3].w += pv.w * vv.w;
    }
    // newest token: cache row held the pre-update value; swap in v_new
    if (chunk == (ctx >> 8)) {
        const int tc = ctx - t0;
        if (proc == (tc & (NPROC - 1))) {
            const int    blk = bt_s[tc >> 4];
            const size_t a   = (((size_t)blk * BLKSZ + (tc & 15)) * KVHEADS + kvh) * HSZ + d0;
            const float4 vo  = *(const float4*)(v_cache + a);
            const float4 vn  = *(const float4*)(v_new + ((size_t)b * KVHEADS + kvh) * HSZ + d0);
            const float4 pv  = *(const float4*)&sp[tc][0];
            const float4 dv  = make_float4(vn.x - vo.x, vn.y - vo.y, vn.z - vo.z, vn.w - vo.w);
            o[0].x += pv.x * dv.x; o[0].y += pv.x * dv.y; o[0].z += pv.x * dv.z; o[0].w += pv.x * dv.w;
            o[1].x += pv.y * dv.x; o[1].y += pv.y * dv.y; o[1].z += pv.y * dv.z; o[1].w += pv.y * dv.w;
            o[2].x += pv.z * dv.x; o[2].y += pv.z * dv.y; o[2].z += pv.z * dv.z; o[2].w += pv.z * dv.w;
            o[3].x += pv.w * dv.x; o[3].y += pv.w * dv.y; o[3].z += pv.w * dv.z; o[3].w += pv.w * dv.w;
        }
    }

    // ---- merge 16 procs (pure adds: m,l are chunk-global) ----
#pragma unroll
    for (int g = 0; g < GRP; ++g) *(float4*)&o_s[proc][g][d0] = o[g];
    __syncthreads();
    {
        const int g = tid >> 7;
        const int d = tid & 127;
        float acc = 0.f;
#pragma unroll
        for (int p = 0; p < NPROC; ++p) acc += o_s[p][g][d];
        const size_t idx = (((size_t)(b * KVHEADS + kvh) * GRP + g) * NSPLIT + chunk);
        if (d == 0) { pm[idx] = m_g; pl[idx] = l_g; }
        po[idx * HSZ + d] = acc;
    }
}

// ---------------- reduce kernel: one WG per (b, kvh) ----------------
__global__ __launch_bounds__(NTHREADS) void pa_reduce(
    const int*  __restrict__ ctx_lens,
    const float* __restrict__ pm, const float* __restrict__ pl,
    const float* __restrict__ po, float* __restrict__ out)
{
    const int b    = blockIdx.x >> 3;
    const int kvh  = blockIdx.x & 7;
    const int ctx  = ctx_lens[b];
    const int nact = (ctx >> 8) + 1;
    const int tid  = threadIdx.x;
    const int g    = tid >> 7;
    const int d    = tid & 127;
    const size_t idx = ((size_t)(b * KVHEADS + kvh) * GRP + g) * NSPLIT;

    float M = -INFINITY;
    for (int p = 0; p < nact; ++p) M = fmaxf(M, pm[idx + p]);
    float L = 0.f, O = 0.f;
    for (int p = 0; p < nact; ++p) {
        const float w = __expf(pm[idx + p] - M);
        L += pl[idx + p] * w;
        O += po[(idx + p) * HSZ + d] * w;
    }
    out[((size_t)b * NHEADS + kvh * GRP + g) * HSZ + d] = O / L;
}

// ---------------- fallback: single kernel (if ws too small) ----------------
__device__ __forceinline__ void proc_row_f(const float4 kv, const float4 vv,
                                           const float4* qf, float* m, float* l,
                                           float4* o) {
    float s[GRP];
#pragma unroll
    for (int g = 0; g < GRP; ++g)
        s[g] = qf[g].x * kv.x + qf[g].y * kv.y + qf[g].z * kv.z + qf[g].w * kv.w;
#pragma unroll
    for (int g = 0; g < GRP; ++g) s[g] = hsum32(s[g]);
#pragma unroll
    for (int g = 0; g < GRP; ++g) {
        const float sc = s[g] * SCALE;
        const float mn = fmaxf(m[g], sc);
        const float cf = __expf(m[g] - mn);
        const float pp = __expf(sc - mn);
        l[g] = l[g] * cf + pp;
        o[g].x = o[g].x * cf + pp * vv.x;
        o[g].y = o[g].y * cf + pp * vv.y;
        o[g].z = o[g].z * cf + pp * vv.z;
        o[g].w = o[g].w * cf + pp * vv.w;
        m[g] = mn;
    }
}

__global__ __launch_bounds__(NTHREADS) void paged_attn_single(
    const float* __restrict__ query, const float* __restrict__ k_new,
    const float* __restrict__ v_new, const float* __restrict__ k_cache,
    const float* __restrict__ v_cache, const int* __restrict__ block_tables,
    const int* __restrict__ ctx_lens, float* __restrict__ out)
{
    const int wg = blockIdx.x, b = wg >> 3, kvh = wg & 7;
    const int tid = threadIdx.x, sub = tid & 31, proc = tid >> 5;
    const int ctx = ctx_lens[b];

    __shared__ float q_s[GRP][HSZ];
    __shared__ float kn_s[HSZ];
    __shared__ int   bt_s[BPS];
    __shared__ float m_s[NPROC][GRP];
    __shared__ float l_s[NPROC][GRP];
    __shared__ float o_s[NPROC][GRP][HSZ];

    {
        const float p = (float)(ctx + 1);
        if (tid < 320) {
            const int   i    = tid & 63;
            const float invf = exp2f(-((float)i / 64.0f) * 13.287712379549449f);
            float s_, c_;
            sincosf(p * invf, &s_, &c_);
            if (tid < 256) {
                const int g = tid >> 6;
                const float* qp = query + ((size_t)b * NHEADS + kvh * GRP + g) * HSZ;
                const float x1 = qp[i], x2 = qp[i + 64];
                q_s[g][i] = x1 * c_ - x2 * s_; q_s[g][i + 64] = x2 * c_ + x1 * s_;
            } else {
                const float* kp = k_new + ((size_t)b * KVHEADS + kvh) * HSZ;
                const float x1 = kp[i], x2 = kp[i + 64];
                kn_s[i] = x1 * c_ - x2 * s_; kn_s[i + 64] = x2 * c_ + x1 * s_;
            }
        } else if (tid < 448) {
            bt_s[tid - 320] = block_tables[b * BPS + (tid - 320)];
        }
    }
    __syncthreads();

    const int d0 = sub << 2;
    float4 qf[GRP];
#pragma unroll
    for (int g = 0; g < GRP; ++g) qf[g] = *(const float4*)&q_s[g][d0];
    float  m[GRP], l[GRP];
    float4 o[GRP];
#pragma unroll
    for (int g = 0; g < GRP; ++g) {
        m[g] = -INFINITY; l[g] = 0.f; o[g] = make_float4(0.f, 0.f, 0.f, 0.f);
    }
    for (int t = proc; t < ctx; t += NPROC) {
        const int    blk = bt_s[t >> 4];
        const size_t a0 = (((size_t)blk * BLKSZ + (t & 15)) * KVHEADS + kvh) * HSZ + d0;
        proc_row_f(*(const float4*)(k_cache + a0), *(const float4*)(v_cache + a0), qf, m, l, o);
    }
    if (proc == (ctx & (NPROC - 1))) {
        proc_row_f(*(const float4*)&kn_s[d0],
                   *(const float4*)(v_new + ((size_t)b * KVHEADS + kvh) * HSZ + d0), qf, m, l, o);
    }
    if (sub == 0) {
#pragma unroll
        for (int g = 0; g < GRP; ++g) { m_s[proc][g] = m[g]; l_s[proc][g] = l[g]; }
    }
#pragma unroll
    for (int g = 0; g < GRP; ++g) *(float4*)&o_s[proc][g][d0] = o[g];
    __syncthreads();
    {
        const int g = tid >> 7, d = tid & 127;
        float mt = -INFINITY;
#pragma unroll
        for (int p = 0; p < NPROC; ++p) mt = fmaxf(mt, m_s[p][g]);
        float lt = 0.f, ot = 0.f;
#pragma unroll
        for (int p = 0; p < NPROC; ++p) {
            const float w = __expf(m_s[p][g] - mt);
            lt += l_s[p][g] * w; ot += o_s[p][g][d] * w;
        }
        out[((size_t)b * NHEADS + kvh * GRP + g) * HSZ + d] = ot / lt;
    }
}

extern "C" void kernel_launch(void* const* d_in, const int* in_sizes, int n_in,
                              void* d_out, int out_size, void* d_ws, size_t ws_size,
                              hipStream_t stream) {
    const float* query        = (const float*)d_in[0];
    const float* k_new        = (const float*)d_in[1];
    const float* v_new        = (const float*)d_in[2];
    const float* k_cache      = (const float*)d_in[3];
    const float* v_cache      = (const float*)d_in[4];
    const int*   block_tables = (const int*)d_in[5];
    const int*   ctx_lens     = (const int*)d_in[6];
    float*       out          = (float*)d_out;

    const size_t NPART = (size_t)BATCH * KVHEADS * GRP * NSPLIT;    // 8192
    const size_t need  = (NPART * 2 + NPART * HSZ) * sizeof(float); // ~4.26 MB

    if (ws_size >= need) {
        float* pm = (float*)d_ws;
        float* pl = pm + NPART;
        float* po = pl + NPART;
        pa_partial<<<dim3(BATCH * KVHEADS * NSPLIT), dim3(NTHREADS), 0, stream>>>(
            query, k_new, v_new, k_cache, v_cache, block_tables, ctx_lens, pm, pl, po);
        pa_reduce<<<dim3(BATCH * KVHEADS), dim3(NTHREADS), 0, stream>>>(
            ctx_lens, pm, pl, po, out);
    } else {
        paged_attn_single<<<dim3(BATCH * KVHEADS), dim3(NTHREADS), 0, stream>>>(
            query, k_new, v_new, k_cache, v_cache, block_tables, ctx_lens, out);
    }
}

// Round 4
// 71.832 us; speedup vs baseline: 1.2775x; 1.2775x over previous
//
#include <hip/hip_runtime.h>
#include <math.h>

#define BATCH    32
#define NHEADS   32
#define KVHEADS  8
#define GRP      4      // NHEADS / KVHEADS
#define HSZ      128
#define BLKSZ    16
#define BPS      128    // blocks per seq
#define NTHREADS 512
#define NPROC    16     // half-wave processors (PV phase)
#define CHUNK    256    // tokens per split
#define NSPLIT   8      // 2048 / CHUNK
#define SCALE    0.08838834764831843f   // 1/sqrt(128)

// ---------------- split kernel: one WG per (b, kvh, chunk) ----------------
__global__ __launch_bounds__(NTHREADS, 8) void pa_partial(
    const float* __restrict__ query,
    const float* __restrict__ k_new,
    const float* __restrict__ v_new,
    const float* __restrict__ k_cache,
    const float* __restrict__ v_cache,
    const int*  __restrict__ block_tables,
    const int*  __restrict__ ctx_lens,
    float* __restrict__ pm, float* __restrict__ pl, float* __restrict__ po)
{
    const int wg    = blockIdx.x;
    const int chunk = wg & (NSPLIT - 1);
    const int kvh   = (wg >> 3) & (KVHEADS - 1);
    const int b     = wg >> 6;
    const int ctx   = ctx_lens[b];
    const int t0    = chunk * CHUNK;
    if (t0 > ctx) return;                 // inactive split: reduce never reads it

    const int tid = threadIdx.x;

    __shared__ float q_s[GRP][HSZ];       // pre-scaled by SCALE
    __shared__ float kn_s[HSZ];
    __shared__ int   bt_s[CHUNK / BLKSZ];
    __shared__ float sp[CHUNK][GRP];      // scores -> probs in place
    __shared__ float redm[8], redl[8];
    __shared__ float o_s[NPROC][GRP][HSZ];

    // ---- init scores to -inf (invalid rows contribute p=0) ----
    {
        float* s1 = &sp[0][0];
        s1[tid]       = -INFINITY;
        s1[tid + 512] = -INFINITY;
    }
    // ---- RoPE (pos = ctx+1) for q heads (pre-scaled) and new k ----
    {
        const float p = (float)(ctx + 1);
        if (tid < 320) {
            const int   i    = tid & 63;
            const float invf = exp2f(-((float)i / 64.0f) * 13.287712379549449f); // 10000^(-2i/128)
            float s_, c_;
            sincosf(p * invf, &s_, &c_);
            if (tid < 256) {
                const int g = tid >> 6;
                const float* qp = query + ((size_t)b * NHEADS + kvh * GRP + g) * HSZ;
                const float x1 = qp[i], x2 = qp[i + 64];
                q_s[g][i]      = (x1 * c_ - x2 * s_) * SCALE;
                q_s[g][i + 64] = (x2 * c_ + x1 * s_) * SCALE;
            } else {
                const float* kp = k_new + ((size_t)b * KVHEADS + kvh) * HSZ;
                const float x1 = kp[i], x2 = kp[i + 64];
                kn_s[i]      = x1 * c_ - x2 * s_;
                kn_s[i + 64] = x2 * c_ + x1 * s_;
            }
        } else if (tid < 320 + CHUNK / BLKSZ) {
            bt_s[tid - 320] = block_tables[b * BPS + (t0 >> 4) + (tid - 320)];
        }
    }
    __syncthreads();

    const int ncache = min(t0 + CHUNK, ctx) - t0;   // rows sourced from cache
    const int lane = tid & 63;
    const int wave = tid >> 6;       // 0..7
    const int rg   = lane >> 2;      // row within 16-row tile
    const int j    = lane & 3;       // dim-slice (32 dims, strided pieces)
    const int jo   = j << 2;         // float offset of piece within 16-float group

    // ---- phase 1: scores, 4 lanes/row, 16 rows/wave, 2 passes ----
#pragma unroll
    for (int pass = 0; pass < 2; ++pass) {
        const int tstart = pass * 128 + wave * 16;
        if (tstart >= ncache) continue;            // wave-uniform skip
        const int tl  = tstart + rg;
        const int blk = bt_s[tstart >> 4];         // wave-uniform (one block per tile)
        const float* kr = k_cache + (((size_t)blk * BLKSZ + rg) * KVHEADS + kvh) * HSZ + jo;
        float s0 = 0.f, s1 = 0.f, s2 = 0.f, s3 = 0.f;
#pragma unroll
        for (int uu = 0; uu < 2; ++uu) {
            float4 kp[4];
#pragma unroll
            for (int u = 0; u < 4; ++u)
                kp[u] = *(const float4*)(kr + (uu * 4 + u) * 16);
#pragma unroll
            for (int u = 0; u < 4; ++u) {
                const int qo = (uu * 4 + u) * 16 + jo;
                const float4 qa = *(const float4*)&q_s[0][qo];
                const float4 qb = *(const float4*)&q_s[1][qo];
                const float4 qc = *(const float4*)&q_s[2][qo];
                const float4 qd = *(const float4*)&q_s[3][qo];
                s0 = fmaf(qa.x, kp[u].x, fmaf(qa.y, kp[u].y, fmaf(qa.z, kp[u].z, fmaf(qa.w, kp[u].w, s0))));
                s1 = fmaf(qb.x, kp[u].x, fmaf(qb.y, kp[u].y, fmaf(qb.z, kp[u].z, fmaf(qb.w, kp[u].w, s1))));
                s2 = fmaf(qc.x, kp[u].x, fmaf(qc.y, kp[u].y, fmaf(qc.z, kp[u].z, fmaf(qc.w, kp[u].w, s2))));
                s3 = fmaf(qd.x, kp[u].x, fmaf(qd.y, kp[u].y, fmaf(qd.z, kp[u].z, fmaf(qd.w, kp[u].w, s3))));
            }
        }
        // 2-hop reduce across the 4 dim-slice lanes (all 16 rows at once)
        s0 += __shfl_xor(s0, 1); s0 += __shfl_xor(s0, 2);
        s1 += __shfl_xor(s1, 1); s1 += __shfl_xor(s1, 2);
        s2 += __shfl_xor(s2, 1); s2 += __shfl_xor(s2, 2);
        s3 += __shfl_xor(s3, 1); s3 += __shfl_xor(s3, 2);
        if (j == 0 && tl < ncache)
            *(float4*)&sp[tl][0] = make_float4(s0, s1, s2, s3);
    }
    // newest token (t == ctx): score from roped k_new in LDS (wave 0 computes)
    if (chunk == (ctx >> 8) && wave == 0) {
        const int tc = ctx - t0;
        float s0 = 0.f, s1 = 0.f, s2 = 0.f, s3 = 0.f;
#pragma unroll
        for (int u = 0; u < 8; ++u) {
            const int qo = u * 16 + jo;
            const float4 kp = *(const float4*)&kn_s[qo];
            const float4 qa = *(const float4*)&q_s[0][qo];
            const float4 qb = *(const float4*)&q_s[1][qo];
            const float4 qc = *(const float4*)&q_s[2][qo];
            const float4 qd = *(const float4*)&q_s[3][qo];
            s0 = fmaf(qa.x, kp.x, fmaf(qa.y, kp.y, fmaf(qa.z, kp.z, fmaf(qa.w, kp.w, s0))));
            s1 = fmaf(qb.x, kp.x, fmaf(qb.y, kp.y, fmaf(qb.z, kp.z, fmaf(qb.w, kp.w, s1))));
            s2 = fmaf(qc.x, kp.x, fmaf(qc.y, kp.y, fmaf(qc.z, kp.z, fmaf(qc.w, kp.w, s2))));
            s3 = fmaf(qd.x, kp.x, fmaf(qd.y, kp.y, fmaf(qd.z, kp.z, fmaf(qd.w, kp.w, s3))));
        }
        s0 += __shfl_xor(s0, 1); s0 += __shfl_xor(s0, 2);
        s1 += __shfl_xor(s1, 1); s1 += __shfl_xor(s1, 2);
        s2 += __shfl_xor(s2, 1); s2 += __shfl_xor(s2, 2);
        s3 += __shfl_xor(s3, 1); s3 += __shfl_xor(s3, 2);
        if (lane == 0) *(float4*)&sp[tc][0] = make_float4(s0, s1, s2, s3);
    }
    __syncthreads();

    // ---- phase 2: chunk-wide softmax ----
    const int g2 = tid >> 7;
    const int t2 = (tid & 127) << 1;
    const float a0 = sp[t2][g2], a1 = sp[t2 + 1][g2];
    float mx = fmaxf(a0, a1);
    mx = fmaxf(mx, __shfl_xor(mx, 1));
    mx = fmaxf(mx, __shfl_xor(mx, 2));
    mx = fmaxf(mx, __shfl_xor(mx, 4));
    mx = fmaxf(mx, __shfl_xor(mx, 8));
    mx = fmaxf(mx, __shfl_xor(mx, 16));
    mx = fmaxf(mx, __shfl_xor(mx, 32));
    if ((tid & 63) == 0) redm[tid >> 6] = mx;
    __syncthreads();
    const float m_g = fmaxf(redm[g2 << 1], redm[(g2 << 1) + 1]);
    const float p0 = __expf(a0 - m_g);
    const float p1 = __expf(a1 - m_g);
    sp[t2][g2]     = p0;
    sp[t2 + 1][g2] = p1;
    float ls = p0 + p1;
    ls += __shfl_xor(ls, 1);
    ls += __shfl_xor(ls, 2);
    ls += __shfl_xor(ls, 4);
    ls += __shfl_xor(ls, 8);
    ls += __shfl_xor(ls, 16);
    ls += __shfl_xor(ls, 32);
    if ((tid & 63) == 0) redl[tid >> 6] = ls;
    __syncthreads();
    const float l_g = redl[g2 << 1] + redl[(g2 << 1) + 1];

    // ---- phase 3: PV, 32 lanes x 4 dims, bounded by ncache ----
    const int sub  = tid & 31;
    const int proc = tid >> 5;
    const int d0   = sub << 2;
    float4 o[GRP];
#pragma unroll
    for (int g = 0; g < GRP; ++g) o[g] = make_float4(0.f, 0.f, 0.f, 0.f);
#pragma unroll 4
    for (int tl = proc; tl < ncache; tl += NPROC) {
        const int    blk = bt_s[tl >> 4];
        const size_t a   = (((size_t)blk * BLKSZ + (tl & 15)) * KVHEADS + kvh) * HSZ + d0;
        const float4 vv  = *(const float4*)(v_cache + a);
        const float4 pv  = *(const float4*)&sp[tl][0];
        o[0].x += pv.x * vv.x; o[0].y += pv.x * vv.y; o[0].z += pv.x * vv.z; o[0].w += pv.x * vv.w;
        o[1].x += pv.y * vv.x; o[1].y += pv.y * vv.y; o[1].z += pv.y * vv.z; o[1].w += pv.y * vv.w;
        o[2].x += pv.z * vv.x; o[2].y += pv.z * vv.y; o[2].z += pv.z * vv.z; o[2].w += pv.z * vv.w;
        o[3].x += pv.w * vv.x; o[3].y += pv.w * vv.y; o[3].z += pv.w * vv.z; o[3].w += pv.w * vv.w;
    }
    // newest token: loop above excluded row tc, so add p*v_new directly
    if (chunk == (ctx >> 8)) {
        const int tc = ctx - t0;
        if (proc == (tc & (NPROC - 1))) {
            const float4 vn = *(const float4*)(v_new + ((size_t)b * KVHEADS + kvh) * HSZ + d0);
            const float4 pv = *(const float4*)&sp[tc][0];
            o[0].x += pv.x * vn.x; o[0].y += pv.x * vn.y; o[0].z += pv.x * vn.z; o[0].w += pv.x * vn.w;
            o[1].x += pv.y * vn.x; o[1].y += pv.y * vn.y; o[1].z += pv.y * vn.z; o[1].w += pv.y * vn.w;
            o[2].x += pv.z * vn.x; o[2].y += pv.z * vn.y; o[2].z += pv.z * vn.z; o[2].w += pv.z * vn.w;
            o[3].x += pv.w * vn.x; o[3].y += pv.w * vn.y; o[3].z += pv.w * vn.z; o[3].w += pv.w * vn.w;
        }
    }

    // ---- merge 16 procs (pure adds: m,l are chunk-global) ----
#pragma unroll
    for (int g = 0; g < GRP; ++g) *(float4*)&o_s[proc][g][d0] = o[g];
    __syncthreads();
    {
        const int g = tid >> 7;
        const int d = tid & 127;
        float acc = 0.f;
#pragma unroll
        for (int p = 0; p < NPROC; ++p) acc += o_s[p][g][d];
        const size_t idx = (((size_t)(b * KVHEADS + kvh) * GRP + g) * NSPLIT + chunk);
        if (d == 0) { pm[idx] = m_g; pl[idx] = l_g; }
        po[idx * HSZ + d] = acc;
    }
}

// ---------------- reduce kernel: one WG per (b, kvh) ----------------
__global__ __launch_bounds__(NTHREADS) void pa_reduce(
    const int*  __restrict__ ctx_lens,
    const float* __restrict__ pm, const float* __restrict__ pl,
    const float* __restrict__ po, float* __restrict__ out)
{
    const int b    = blockIdx.x >> 3;
    const int kvh  = blockIdx.x & 7;
    const int ctx  = ctx_lens[b];
    const int nact = (ctx >> 8) + 1;
    const int tid  = threadIdx.x;
    const int g    = tid >> 7;
    const int d    = tid & 127;
    const size_t idx = ((size_t)(b * KVHEADS + kvh) * GRP + g) * NSPLIT;

    float M = -INFINITY;
    for (int p = 0; p < nact; ++p) M = fmaxf(M, pm[idx + p]);
    float L = 0.f, O = 0.f;
    for (int p = 0; p < nact; ++p) {
        const float w = __expf(pm[idx + p] - M);
        L += pl[idx + p] * w;
        O += po[(idx + p) * HSZ + d] * w;
    }
    out[((size_t)b * NHEADS + kvh * GRP + g) * HSZ + d] = O / L;
}

// ---------------- fallback: single kernel (if ws too small) ----------------
__device__ __forceinline__ float hsum32(float v) {
    v += __shfl_xor(v, 1);
    v += __shfl_xor(v, 2);
    v += __shfl_xor(v, 4);
    v += __shfl_xor(v, 8);
    v += __shfl_xor(v, 16);
    return v;
}

__device__ __forceinline__ void proc_row_f(const float4 kv, const float4 vv,
                                           const float4* qf, float* m, float* l,
                                           float4* o) {
    float s[GRP];
#pragma unroll
    for (int g = 0; g < GRP; ++g)
        s[g] = qf[g].x * kv.x + qf[g].y * kv.y + qf[g].z * kv.z + qf[g].w * kv.w;
#pragma unroll
    for (int g = 0; g < GRP; ++g) s[g] = hsum32(s[g]);
#pragma unroll
    for (int g = 0; g < GRP; ++g) {
        const float sc = s[g] * SCALE;
        const float mn = fmaxf(m[g], sc);
        const float cf = __expf(m[g] - mn);
        const float pp = __expf(sc - mn);
        l[g] = l[g] * cf + pp;
        o[g].x = o[g].x * cf + pp * vv.x;
        o[g].y = o[g].y * cf + pp * vv.y;
        o[g].z = o[g].z * cf + pp * vv.z;
        o[g].w = o[g].w * cf + pp * vv.w;
        m[g] = mn;
    }
}

__global__ __launch_bounds__(NTHREADS) void paged_attn_single(
    const float* __restrict__ query, const float* __restrict__ k_new,
    const float* __restrict__ v_new, const float* __restrict__ k_cache,
    const float* __restrict__ v_cache, const int* __restrict__ block_tables,
    const int* __restrict__ ctx_lens, float* __restrict__ out)
{
    const int wg = blockIdx.x, b = wg >> 3, kvh = wg & 7;
    const int tid = threadIdx.x, sub = tid & 31, proc = tid >> 5;
    const int ctx = ctx_lens[b];

    __shared__ float q_s[GRP][HSZ];
    __shared__ float kn_s[HSZ];
    __shared__ int   bt_s[BPS];
    __shared__ float m_s[NPROC][GRP];
    __shared__ float l_s[NPROC][GRP];
    __shared__ float o_s[NPROC][GRP][HSZ];

    {
        const float p = (float)(ctx + 1);
        if (tid < 320) {
            const int   i    = tid & 63;
            const float invf = exp2f(-((float)i / 64.0f) * 13.287712379549449f);
            float s_, c_;
            sincosf(p * invf, &s_, &c_);
            if (tid < 256) {
                const int g = tid >> 6;
                const float* qp = query + ((size_t)b * NHEADS + kvh * GRP + g) * HSZ;
                const float x1 = qp[i], x2 = qp[i + 64];
                q_s[g][i] = x1 * c_ - x2 * s_; q_s[g][i + 64] = x2 * c_ + x1 * s_;
            } else {
                const float* kp = k_new + ((size_t)b * KVHEADS + kvh) * HSZ;
                const float x1 = kp[i], x2 = kp[i + 64];
                kn_s[i] = x1 * c_ - x2 * s_; kn_s[i + 64] = x2 * c_ + x1 * s_;
            }
        } else if (tid < 448) {
            bt_s[tid - 320] = block_tables[b * BPS + (tid - 320)];
        }
    }
    __syncthreads();

    const int d0 = sub << 2;
    float4 qf[GRP];
#pragma unroll
    for (int g = 0; g < GRP; ++g) qf[g] = *(const float4*)&q_s[g][d0];
    float  m[GRP], l[GRP];
    float4 o[GRP];
#pragma unroll
    for (int g = 0; g < GRP; ++g) {
        m[g] = -INFINITY; l[g] = 0.f; o[g] = make_float4(0.f, 0.f, 0.f, 0.f);
    }
    for (int t = proc; t < ctx; t += NPROC) {
        const int    blk = bt_s[t >> 4];
        const size_t a0 = (((size_t)blk * BLKSZ + (t & 15)) * KVHEADS + kvh) * HSZ + d0;
        proc_row_f(*(const float4*)(k_cache + a0), *(const float4*)(v_cache + a0), qf, m, l, o);
    }
    if (proc == (ctx & (NPROC - 1))) {
        proc_row_f(*(const float4*)&kn_s[d0],
                   *(const float4*)(v_new + ((size_t)b * KVHEADS + kvh) * HSZ + d0), qf, m, l, o);
    }
    if (sub == 0) {
#pragma unroll
        for (int g = 0; g < GRP; ++g) { m_s[proc][g] = m[g]; l_s[proc][g] = l[g]; }
    }
#pragma unroll
    for (int g = 0; g < GRP; ++g) *(float4*)&o_s[proc][g][d0] = o[g];
    __syncthreads();
    {
        const int g = tid >> 7, d = tid & 127;
        float mt = -INFINITY;
#pragma unroll
        for (int p = 0; p < NPROC; ++p) mt = fmaxf(mt, m_s[p][g]);
        float lt = 0.f, ot = 0.f;
#pragma unroll
        for (int p = 0; p < NPROC; ++p) {
            const float w = __expf(m_s[p][g] - mt);
            lt += l_s[p][g] * w; ot += o_s[p][g][d] * w;
        }
        out[((size_t)b * NHEADS + kvh * GRP + g) * HSZ + d] = ot / lt;
    }
}

extern "C" void kernel_launch(void* const* d_in, const int* in_sizes, int n_in,
                              void* d_out, int out_size, void* d_ws, size_t ws_size,
                              hipStream_t stream) {
    const float* query        = (const float*)d_in[0];
    const float* k_new        = (const float*)d_in[1];
    const float* v_new        = (const float*)d_in[2];
    const float* k_cache      = (const float*)d_in[3];
    const float* v_cache      = (const float*)d_in[4];
    const int*   block_tables = (const int*)d_in[5];
    const int*   ctx_lens     = (const int*)d_in[6];
    float*       out          = (float*)d_out;

    const size_t NPART = (size_t)BATCH * KVHEADS * GRP * NSPLIT;    // 8192
    const size_t need  = (NPART * 2 + NPART * HSZ) * sizeof(float); // ~4.26 MB

    if (ws_size >= need) {
        float* pm = (float*)d_ws;
        float* pl = pm + NPART;
        float* po = pl + NPART;
        pa_partial<<<dim3(BATCH * KVHEADS * NSPLIT), dim3(NTHREADS), 0, stream>>>(
            query, k_new, v_new, k_cache, v_cache, block_tables, ctx_lens, pm, pl, po);
        pa_reduce<<<dim3(BATCH * KVHEADS), dim3(NTHREADS), 0, stream>>>(
            ctx_lens, pm, pl, po, out);
    } else {
        paged_attn_single<<<dim3(BATCH * KVHEADS), dim3(NTHREADS), 0, stream>>>(
            query, k_new, v_new, k_cache, v_cache, block_tables, ctx_lens, out);
    }
}